// Round 9
// baseline (254.846 us; speedup 1.0000x reference)
//
#include <hip/hip_runtime.h>
#include <hip/hip_bf16.h>

// q = x@Wq^T*scale; k = y@Wk^T; v = y@Wv^T
// out = strict_lower(q@k^T) @ v  -- causal LINEAR attention:
//   out_t = q_t @ P_t + strict_tril(q_t k_t^T) @ v_t,  P_t = sum_{c<t} k_c^T v_c
//
// v14 (from v13 @ 253.5us):
//  * Tail attack. hs_gemm/out_gemm were 1-phase BK=64 loops whose time is
//    (#serial barrier rounds) x (load latency): H-part 2 rounds for K=128,
//    out_gemm 10 rounds at 1 block/CU. Switch both to BK=128 [128][128]
//    bf16 tiles (64KB LDS): ONE 16-load/lane burst per round (2x MLP),
//    64 MFMAs per round. Rounds: H 2->1, S 8->4, out 10->5.
//    16-chunk rows, slot = c ^ (r&15) -> quarter-wave b128 = 2-way = free.
//  * gemm_qkv2 / convert_w / prefix_scan: v13-exact (untouched).
// ws (bf16 elems): q[4M] k[4M] kT[4M] vT[4M] | Ht[16M] Pt[16M]
//   wq(->Sd)/wk/wv[1M x3].

typedef __bf16 bf16x8 __attribute__((ext_vector_type(8)));
typedef __bf16 bf16x4 __attribute__((ext_vector_type(4)));
typedef __bf16 bf16x2 __attribute__((ext_vector_type(2)));
typedef float f32x4 __attribute__((ext_vector_type(4)));

#define MFMA16(a, b, c) __builtin_amdgcn_mfma_f32_16x16x32_bf16(a, b, c, 0, 0, 0)

constexpr float SCALE = 0.04419417382415922f; // 1/sqrt(512)

__device__ __forceinline__ void ld16(const void* g, void* l) {
    __builtin_amdgcn_global_load_lds(
        (__attribute__((address_space(1))) void*)g,
        (__attribute__((address_space(3))) void*)l, 16, 0, 0);
}

// ---- [128][64] bf16 tile machinery (gemm_qkv2, v13-exact) ----
// data-chunk c (16B) of row r, 128B rows (8 slots), slot = c ^ (r&7).
__device__ __forceinline__ bf16x8 frag(const __bf16* base, int r, int c) {
    return *(const bf16x8*)((const char*)base + r * 128 + ((c ^ (r & 7)) * 16));
}

// fp32 [128][64] tile (256B rows, 16 slots), slot = c ^ (r&15); cvt to bf16x8.
__device__ __forceinline__ bf16x8 fragA32(const float* base, int r, int c0) {
    const char* rowp = (const char*)base + r * 256;
    f32x4 a = *(const f32x4*)(rowp + ((c0 ^ (r & 15)) * 16));
    f32x4 b = *(const f32x4*)(rowp + (((c0 + 1) ^ (r & 15)) * 16));
    bf16x8 o;
    o[0] = (__bf16)a[0]; o[1] = (__bf16)a[1];
    o[2] = (__bf16)a[2]; o[3] = (__bf16)a[3];
    o[4] = (__bf16)b[0]; o[5] = (__bf16)b[1];
    o[6] = (__bf16)b[2]; o[7] = (__bf16)b[3];
    return o;
}

// ---- [128][128] bf16 tile machinery (hs_gemm/out_gemm, new) ----
// 256B rows = 16 chunks of 16B; slot = c ^ (r&15).
__device__ __forceinline__ bf16x8 frag128(const __bf16* base, int r, int c) {
    return *(const bf16x8*)((const char*)base + r * 256 + ((c ^ (r & 15)) * 16));
}

// Stage a full [128][128] bf16 tile: src points at [row0=0][k0]; row stride
// rs elems. 8 ld16/lane. Issue u covers rows u*4 + (lane>>4) of this wave's
// 32-row group; lane&15 = LDS slot; source chunk = slot ^ (row&15).
__device__ __forceinline__ void stage128(const __bf16* src, size_t rs,
                                         __bf16* lds, int wave, int lane) {
    const int lr4 = lane >> 4;       // row within 4-row issue group
    const int sl  = lane & 15;       // LDS slot this lane fills
    __bf16* dst = lds + wave * 4096 + lane * 8;
#pragma unroll
    for (int u = 0; u < 8; ++u) {
        const int rloc = u * 4 + lr4;                  // 0..31 within wave
        const int c = sl ^ (rloc & 15);                // wave*32 % 16 == 0
        ld16(src + (size_t)(wave * 32 + rloc) * rs + c * 8, dst + u * 512);
    }
}

__device__ inline bf16x4 pack4(float4 a) {
    bf16x4 r;
    r[0] = (__bf16)a.x; r[1] = (__bf16)a.y;
    r[2] = (__bf16)a.z; r[3] = (__bf16)a.w;
    return r;
}

// ---------------------------------------------------------------------------
// Weights fp32 -> bf16 only. Wave owns 512 contiguous floats. 6144 waves.
// ---------------------------------------------------------------------------
__global__ __launch_bounds__(256) void convert_w(
    const float* __restrict__ wqf, const float* __restrict__ wkf,
    const float* __restrict__ wvf, __bf16* __restrict__ wqb,
    __bf16* __restrict__ wkb, __bf16* __restrict__ wvb)
{
    const size_t tid = (size_t)blockIdx.x * 256 + threadIdx.x;
    const size_t w = tid >> 6;
    const int lane = (int)(tid & 63);
    size_t f = w * 512;
    const float* src; __bf16* dst;
    if (f < 1048576)      { src = wqf; dst = wqb; }
    else if (f < 2097152) { src = wkf; dst = wkb; f -= 1048576; }
    else                  { src = wvf; dst = wvb; f -= 2097152; }
    const float4* s4 = (const float4*)(src + f);
    float4 a = s4[lane];
    float4 b = s4[64 + lane];
    __bf16* d = dst + f;
    *(bf16x4*)(d + lane * 4)       = pack4(a);
    *(bf16x4*)(d + 256 + lane * 4) = pack4(b);
}

// ---------------------------------------------------------------------------
// Fused q/kv GEMM (v10/v13-exact). grid (64, 8): m0 = x*128, n0 = (y>>1)*128:
//   y even (q-block):  acc0 = bf16(x_t) @ Wq^T -> qo (SCALE folded)
//   y odd  (kv-block): acc0 = bf16(y_t) @ Wk^T -> ko + kT
//                      acc1 = bf16(y_t) @ Wv^T -> vT  (same staged A!)
// ---------------------------------------------------------------------------
__global__ __launch_bounds__(256, 2) void gemm_qkv2(
    const float* __restrict__ x, const float* __restrict__ y,
    const __bf16* __restrict__ wq, const __bf16* __restrict__ wk,
    const __bf16* __restrict__ wv, __bf16* __restrict__ qo,
    __bf16* __restrict__ ko, __bf16* __restrict__ kT,
    __bf16* __restrict__ vT)
{
    constexpr int K = 2048, N = 512;
    __shared__ __align__(16) float  Asf[128][64];     // 32 KB
    __shared__ __align__(16) __bf16 Bs[2][128][64];   // 32 KB

    const bool iskv = (blockIdx.y & 1) != 0;
    const float* A = iskv ? y : x;
    const __bf16* B0 = iskv ? wk : wq;

    const int tid  = threadIdx.x;
    const int wave = tid >> 6, lane = tid & 63;
    const int fr = lane & 15, fq = lane >> 4;
    const int m0 = blockIdx.x * 128, n0 = (blockIdx.y >> 1) * 128;
    const int wr = (wave >> 1) * 64, wc = (wave & 1) * 64;
    const int lr = lane >> 3;            // B staging: row within 8-row group
    const int cd = (lane & 7) ^ lr;      // B staging: swizzled chunk
    const int lr4 = lane >> 4;           // A staging: row within 4-row group
    const int cl  = lane & 15;           // A staging: LDS slot (16 per row)

    f32x4 acc0[4][4], acc1[4][4];
#pragma unroll
    for (int a = 0; a < 4; ++a)
#pragma unroll
        for (int b = 0; b < 4; ++b) {
            acc0[a][b] = f32x4{0.f, 0.f, 0.f, 0.f};
            acc1[a][b] = f32x4{0.f, 0.f, 0.f, 0.f};
        }

    const __bf16* bg0 = B0 + (size_t)(n0 + wave * 32 + lr) * K + cd * 8;
    const __bf16* bg1 = wv + (size_t)(n0 + wave * 32 + lr) * K + cd * 8;
    float*  alf = &Asf[wave * 32][0];
    __bf16* bl0 = &Bs[0][wave * 32][0];
    __bf16* bl1 = &Bs[1][wave * 32][0];
    const float* ag0 = A + (size_t)(m0 + wave * 32 + lr4) * K;

    for (int kk = 0; kk < K; kk += 64) {
        __syncthreads();                 // prev step's frag reads done
#pragma unroll
        for (int u = 0; u < 4; ++u)
            ld16(bg0 + (size_t)(u * 8) * K + kk, bl0 + u * 512);
        if (iskv) {
#pragma unroll
            for (int u = 0; u < 4; ++u)
                ld16(bg1 + (size_t)(u * 8) * K + kk, bl1 + u * 512);
        }
#pragma unroll
        for (int u = 0; u < 8; ++u) {
            const int rw = u * 4 + lr4;          // row within wave group
            const int c  = cl ^ (rw & 15);       // source data chunk
            ld16(ag0 + (size_t)(u * 4) * K + kk + c * 4, alf + u * 256);
        }
        __syncthreads();                 // drains vmcnt: tiles visible
#pragma unroll
        for (int ks = 0; ks < 2; ++ks) {
            bf16x8 af[4], bf[4];
#pragma unroll
            for (int rt = 0; rt < 4; ++rt)
                af[rt] = fragA32(&Asf[0][0], wr + rt * 16 + fr, ks * 8 + fq * 2);
#pragma unroll
            for (int nt = 0; nt < 4; ++nt)
                bf[nt] = frag(&Bs[0][0][0], wc + nt * 16 + fr, ks * 4 + fq);
#pragma unroll
            for (int rt = 0; rt < 4; ++rt)
#pragma unroll
                for (int nt = 0; nt < 4; ++nt)
                    acc0[rt][nt] = MFMA16(af[rt], bf[nt], acc0[rt][nt]);
            if (iskv) {
                bf16x8 bg[4];
#pragma unroll
                for (int nt = 0; nt < 4; ++nt)
                    bg[nt] = frag(&Bs[1][0][0], wc + nt * 16 + fr, ks * 4 + fq);
#pragma unroll
                for (int rt = 0; rt < 4; ++rt)
#pragma unroll
                    for (int nt = 0; nt < 4; ++nt)
                        acc1[rt][nt] = MFMA16(af[rt], bg[nt], acc1[rt][nt]);
            }
        }
    }

    if (!iskv) {
#pragma unroll
        for (int rt = 0; rt < 4; ++rt)
#pragma unroll
            for (int nt = 0; nt < 4; ++nt) {
                const int col = n0 + wc + nt * 16 + fr;
#pragma unroll
                for (int r = 0; r < 4; ++r) {
                    const int row = m0 + wr + rt * 16 + fq * 4 + r;
                    qo[(size_t)row * N + col] = (__bf16)(acc0[rt][nt][r] * SCALE);
                }
            }
    } else {
#pragma unroll
        for (int rt = 0; rt < 4; ++rt)
#pragma unroll
            for (int nt = 0; nt < 4; ++nt) {
                const int col  = n0 + wc + nt * 16 + fr;
                const int row0 = m0 + wr + rt * 16 + fq * 4;
                bf16x4 k4, v4;
#pragma unroll
                for (int r = 0; r < 4; ++r) {
                    k4[r] = (__bf16)acc0[rt][nt][r];
                    v4[r] = (__bf16)acc1[rt][nt][r];
                    ko[(size_t)(row0 + r) * N + col] = k4[r];
                }
                *(bf16x4*)(kT + (size_t)col * 8192 + row0) = k4;
                *(bf16x4*)(vT + (size_t)col * 8192 + row0) = v4;
            }
    }
}

// ---------------------------------------------------------------------------
// Merged H + diagonal-S launch, grid (16, 67), BK=128 single-burst rounds:
//  y <  63: Ht[c][n][d] = (vT_c @ kT_c^T), c = y, K=128 -> ONE round
//  y >= 63: Sd[t] = strict_tril(q_t @ k_t^T), t = (y-63)*16 + x, K=512 -> 4
// Each round: 16 ld16/lane burst -> barrier -> 64 MFMA. 64KB LDS, 2/CU.
// ---------------------------------------------------------------------------
__global__ __launch_bounds__(256, 2) void hs_gemm(
    const __bf16* __restrict__ vT, const __bf16* __restrict__ kT,
    const __bf16* __restrict__ q, const __bf16* __restrict__ k,
    __bf16* __restrict__ Ht, __bf16* __restrict__ Sd)
{
    __shared__ __align__(16) __bf16 As[128][128];   // 32 KB
    __shared__ __align__(16) __bf16 Bs[128][128];   // 32 KB

    const int tid  = threadIdx.x;
    const int wave = tid >> 6, lane = tid & 63;
    const int fr = lane & 15, fq = lane >> 4;
    const int wr = (wave >> 1) * 64, wc = (wave & 1) * 64;

    f32x4 acc[4][4];
#pragma unroll
    for (int a = 0; a < 4; ++a)
#pragma unroll
        for (int b = 0; b < 4; ++b) acc[a][b] = f32x4{0.f, 0.f, 0.f, 0.f};

    const bool ish = blockIdx.y < 63;
    const __bf16 *aSrc, *bSrc;
    size_t ars, brs;
    int nrounds;
    if (ish) {
        const int c  = blockIdx.y;
        const int m0 = (blockIdx.x & 3) * 128;  // n (v feature)
        const int n0 = (blockIdx.x >> 2) * 128; // d (k feature)
        aSrc = vT + (size_t)m0 * 8192 + c * 128; ars = 8192;
        bSrc = kT + (size_t)n0 * 8192 + c * 128; brs = 8192;
        nrounds = 1;
    } else {
        const int t = (blockIdx.y - 63) * 16 + blockIdx.x;
        aSrc = q + (size_t)(t * 128) * 512; ars = 512;
        bSrc = k + (size_t)(t * 128) * 512; brs = 512;
        nrounds = 4;
    }

    for (int s = 0; s < nrounds; ++s) {
        __syncthreads();                       // protect prev round's reads
        stage128(aSrc + s * 128, ars, &As[0][0], wave, lane);
        stage128(bSrc + s * 128, brs, &Bs[0][0], wave, lane);
        __syncthreads();                       // burst drained
#pragma unroll
        for (int ks = 0; ks < 4; ++ks) {
            bf16x8 af[4], bf[4];
#pragma unroll
            for (int rt = 0; rt < 4; ++rt)
                af[rt] = frag128(&As[0][0], wr + rt * 16 + fr, ks * 4 + fq);
#pragma unroll
            for (int nt = 0; nt < 4; ++nt)
                bf[nt] = frag128(&Bs[0][0], wc + nt * 16 + fr, ks * 4 + fq);
#pragma unroll
            for (int rt = 0; rt < 4; ++rt)
#pragma unroll
                for (int nt = 0; nt < 4; ++nt)
                    acc[rt][nt] = MFMA16(af[rt], bf[nt], acc[rt][nt]);
        }
    }

    if (ish) {
        const int c  = blockIdx.y;
        const int m0 = (blockIdx.x & 3) * 128;
        const int n0 = (blockIdx.x >> 2) * 128;
        __bf16* tp = Ht + (size_t)c * 262144;
#pragma unroll
        for (int rt = 0; rt < 4; ++rt)
#pragma unroll
            for (int nt = 0; nt < 4; ++nt) {
                const int col = n0 + wc + nt * 16 + fr;
#pragma unroll
                for (int r = 0; r < 4; ++r) {
                    const int row = m0 + wr + rt * 16 + fq * 4 + r;
                    tp[(size_t)row * 512 + col] = (__bf16)acc[rt][nt][r];
                }
            }
    } else {
        const int t = (blockIdx.y - 63) * 16 + blockIdx.x;
        __bf16* tp = Sd + (size_t)t * 16384;
#pragma unroll
        for (int rt = 0; rt < 4; ++rt)
#pragma unroll
            for (int nt = 0; nt < 4; ++nt) {
                const int col = wc + nt * 16 + fr;
#pragma unroll
                for (int r = 0; r < 4; ++r) {
                    const int row = wr + rt * 16 + fq * 4 + r;
                    float vv = (col < row) ? acc[rt][nt][r] : 0.f;
                    tp[row * 128 + col] = (__bf16)vv;
                }
            }
    }
}

// ---------------------------------------------------------------------------
// Exclusive prefix over chunk axis: Pt[c] = sum_{c'<c} Ht[c'], fp32 accum.
// 512 blocks x 256 thr, 2 elems/thread (v13-exact).
// ---------------------------------------------------------------------------
__global__ __launch_bounds__(256) void prefix_scan(
    const __bf16* __restrict__ Ht, __bf16* __restrict__ Pt)
{
    const size_t e = ((size_t)blockIdx.x * 256 + threadIdx.x) * 2;
    float a0 = 0.f, a1 = 0.f;
#pragma unroll 9
    for (int c = 0; c < 63; ++c) {
        bf16x2 h = *(const bf16x2*)(Ht + (size_t)c * 262144 + e);
        a0 += (float)h[0]; a1 += (float)h[1];
        bf16x2 p;
        p[0] = (__bf16)a0; p[1] = (__bf16)a1;
        *(bf16x2*)(Pt + (size_t)(c + 1) * 262144 + e) = p;
    }
}

// ---------------------------------------------------------------------------
// Out kernel, block (t, n0), BK=128 single-burst rounds:
//   rounds 0..3 (t>0 only): acc += q_t @ Pt_t K-slice 128
//   last round:             acc += Sd[t] @ v_t (K=128)
// Non-atomic fp32 store (block owns its 128x128 tile). 64KB LDS.
// ---------------------------------------------------------------------------
__global__ __launch_bounds__(256, 2) void out_gemm(
    const __bf16* __restrict__ q, const __bf16* __restrict__ Sd,
    const __bf16* __restrict__ vT, const __bf16* __restrict__ Pt,
    float* __restrict__ out)
{
    __shared__ __align__(16) __bf16 As[128][128];   // 32 KB
    __shared__ __align__(16) __bf16 Bs[128][128];   // 32 KB

    const int t  = blockIdx.x;
    const int n0 = blockIdx.y * 128;

    const int tid  = threadIdx.x;
    const int wave = tid >> 6, lane = tid & 63;
    const int fr = lane & 15, fq = lane >> 4;
    const int wr = (wave >> 1) * 64, wc = (wave & 1) * 64;

    f32x4 acc[4][4];
#pragma unroll
    for (int a = 0; a < 4; ++a)
#pragma unroll
        for (int b = 0; b < 4; ++b) acc[a][b] = f32x4{0.f, 0.f, 0.f, 0.f};

    const __bf16* qB  = q  + (size_t)(t * 128) * 512;
    const __bf16* ptB = Pt + (size_t)t * 262144 + (size_t)n0 * 512;
    const __bf16* sdB = Sd + (size_t)t * 16384;
    const __bf16* vtB = vT + (size_t)n0 * 8192 + t * 128;

    const int nrounds = (t > 0) ? 5 : 1;

    for (int s = 0; s < nrounds; ++s) {
        const bool last = (s == nrounds - 1);
        __syncthreads();                       // protect prev round's reads
        if (!last) {
            stage128(qB + s * 128,  512, &As[0][0], wave, lane);
            stage128(ptB + s * 128, 512, &Bs[0][0], wave, lane);
        } else {
            stage128(sdB, 128,  &As[0][0], wave, lane);
            stage128(vtB, 8192, &Bs[0][0], wave, lane);
        }
        __syncthreads();                       // burst drained
#pragma unroll
        for (int ks = 0; ks < 4; ++ks) {
            bf16x8 af[4], bf[4];
#pragma unroll
            for (int rt = 0; rt < 4; ++rt)
                af[rt] = frag128(&As[0][0], wr + rt * 16 + fr, ks * 4 + fq);
#pragma unroll
            for (int nt = 0; nt < 4; ++nt)
                bf[nt] = frag128(&Bs[0][0], wc + nt * 16 + fr, ks * 4 + fq);
#pragma unroll
            for (int rt = 0; rt < 4; ++rt)
#pragma unroll
                for (int nt = 0; nt < 4; ++nt)
                    acc[rt][nt] = MFMA16(af[rt], bf[nt], acc[rt][nt]);
        }
    }

    // epilogue: exclusive owner of this 128x128 tile -> plain fp32 store
#pragma unroll
    for (int rt = 0; rt < 4; ++rt)
#pragma unroll
        for (int nt = 0; nt < 4; ++nt) {
            const int col = n0 + wc + nt * 16 + fr;
#pragma unroll
            for (int r = 0; r < 4; ++r) {
                const int row = t * 128 + wr + rt * 16 + fq * 4 + r;
                out[(size_t)row * 512 + col] = acc[rt][nt][r];
            }
        }
}

// ---------------------------------------------------------------------------
extern "C" void kernel_launch(void* const* d_in, const int* in_sizes, int n_in,
                              void* d_out, int out_size, void* d_ws, size_t ws_size,
                              hipStream_t stream) {
    const float* x  = (const float*)d_in[0];
    const float* y  = (const float*)d_in[1];
    const float* Wq = (const float*)d_in[2];
    const float* Wk = (const float*)d_in[3];
    const float* Wv = (const float*)d_in[4];
    float* out = (float*)d_out;

    const size_t QK = (size_t)8192 * 512;       // 4194304
    __bf16* q  = (__bf16*)d_ws;
    __bf16* k  = q + QK;
    __bf16* kT = k + QK;
    __bf16* vT = kT + QK;
    __bf16* Ht  = vT + QK;                      // 16777216-elem region
    __bf16* Pt  = Ht + 16777216;                // 16777216-elem region
    __bf16* wqb = Pt + 16777216;
    __bf16* wkb = wqb + 1048576;
    __bf16* wvb = wkb + 1048576;
    __bf16* Sd = wqb;                           // alias: wqb dead after gemm

    convert_w<<<1536, 256, 0, stream>>>(Wq, Wk, Wv, wqb, wkb, wvb);
    gemm_qkv2<<<dim3(64, 8), 256, 0, stream>>>(x, y, wqb, wkb, wvb, q, k, kT, vT);
    hs_gemm<<<dim3(16, 67), 256, 0, stream>>>(vT, kT, q, k, Ht, Sd);
    prefix_scan<<<512, 256, 0, stream>>>(Ht, Pt);
    out_gemm<<<dim3(64, 4), 256, 0, stream>>>(q, Sd, vT, Pt, out);
}